// Round 5
// baseline (39.298 us; speedup 1.0000x reference)
//
#include <hip/hip_runtime.h>
#include <hip/hip_bf16.h>

// Problem constants (match reference)
#define VOCAB 50000
#define BB 64
#define TT 512
#define CC 512
#define HALF 50
#define WW 101             // window = 2*HALF+1
#define ROWS (BB * TT)     // 32768 (b,t) rows
#define RPW 4              // rows per wave (all same b)
// block = 256 threads = 4 waves * 4 rows = 16 rows; 512 % 16 == 0 so each
// block stays within one b. grid = 32768/16 = 2048.

typedef float vfloat4 __attribute__((ext_vector_type(4)));

__global__ __launch_bounds__(256) void TimeAttention_38345468019460_kernel(
    const int*   __restrict__ concepts,   // [B*T]
    const int*   __restrict__ tts,        // [B*T]
    const int*   __restrict__ cts,        // [B*C]
    const int*   __restrict__ mask,       // [B*C]
    const float* __restrict__ emb,        // [VOCAB*W]
    float*       __restrict__ out)        // [B*T*C]
{
    const int wid  = threadIdx.x >> 6;
    const int lane = threadIdx.x & 63;
    const int rowbase = __builtin_amdgcn_readfirstlane(blockIdx.x * 16 + wid * RPW);
    const int b       = rowbase >> 9;     // T = 512

    // Context slots + mask: loaded ONCE per wave, reused by all 4 rows.
    const int cbase = b * CC + lane * 8;
    int4 ct0 = *(const int4*)(cts  + cbase);
    int4 ct1 = *(const int4*)(cts  + cbase + 4);
    int4 mk0 = *(const int4*)(mask + cbase);
    int4 mk1 = *(const int4*)(mask + cbase + 4);
    int   cc[8] = {ct0.x, ct0.y, ct0.z, ct0.w, ct1.x, ct1.y, ct1.z, ct1.w};
    float fm[8];
    {
        int mm[8] = {mk0.x, mk0.y, mk0.z, mk0.w, mk1.x, mk1.y, mk1.z, mk1.w};
        #pragma unroll
        for (int j = 0; j < 8; ++j) fm[j] = mm[j] ? -1e9f : 0.0f;
    }

    // Scalar per-row params (uniform -> SGPR loads, all issued up front)
    int tadj[RPW];
    const float* erow[RPW];
    #pragma unroll
    for (int r = 0; r < RPW; ++r) {
        tadj[r] = tts[rowbase + r] - HALF;
        erow[r] = emb + (long)concepts[rowbase + r] * WW;
    }

    // Stage 4 rows' embedding windows into this wave's private LDS slab.
    // (Known-good R3 gather path: broadcast-dominated ds_read, ~0 conflicts.)
    __shared__ float semb[4][RPW][104];
    #pragma unroll
    for (int r = 0; r < RPW; ++r) {
        semb[wid][r][lane] = erow[r][lane];
        if (lane < WW - 64) semb[wid][r][lane + 64] = erow[r][lane + 64];
    }
    __builtin_amdgcn_wave_barrier();   // wave-private region: no block barrier

    // 4 independent gather->exp->reduce->store chains; scheduler overlaps them.
    #pragma unroll
    for (int r = 0; r < RPW; ++r) {
        float p[8];
        float s = 0.0f;
        #pragma unroll
        for (int j = 0; j < 8; ++j) {
            int d = cc[j] - tadj[r];
            d = min(max(d, 0), WW - 1);                 // v_sub + v_med3
            p[j] = __expf(semb[wid][r][d] + fm[j]);     // masked -> exp(-1e9)=0
            s += p[j];
        }
        #pragma unroll
        for (int off = 32; off; off >>= 1) s += __shfl_xor(s, off);

        const float inv = __builtin_amdgcn_rcpf(s);
        vfloat4 o0 = {p[0] * inv, p[1] * inv, p[2] * inv, p[3] * inv};
        vfloat4 o1 = {p[4] * inv, p[5] * inv, p[6] * inv, p[7] * inv};
        const long obase = (long)(rowbase + r) * CC + lane * 8;
        __builtin_nontemporal_store(o0, (vfloat4*)(out + obase));
        __builtin_nontemporal_store(o1, (vfloat4*)(out + obase + 4));
    }
}

extern "C" void kernel_launch(void* const* d_in, const int* in_sizes, int n_in,
                              void* d_out, int out_size, void* d_ws, size_t ws_size,
                              hipStream_t stream) {
    const int*   concepts = (const int*)d_in[0];
    const int*   tts      = (const int*)d_in[1];
    const int*   cts      = (const int*)d_in[2];
    const int*   mask     = (const int*)d_in[3];
    const float* emb      = (const float*)d_in[4];
    float*       out      = (float*)d_out;

    const int blocks = ROWS / (4 * RPW);   // 2048
    TimeAttention_38345468019460_kernel<<<blocks, 256, 0, stream>>>(
        concepts, tts, cts, mask, emb, out);
}

// Round 6
// 22.620 us; speedup vs baseline: 1.7373x; 1.7373x over previous
//
#include <hip/hip_runtime.h>
#include <hip/hip_bf16.h>

// Problem constants (match reference)
#define VOCAB 50000
#define BB 64
#define TT 512
#define CC 512
#define HALF 50
#define WW 101            // window = 2*HALF+1
#define ROWS (BB * TT)    // 32768 rows, one wave each (R3 structure: best so far)

typedef float vfloat4 __attribute__((ext_vector_type(4)));

__global__ __launch_bounds__(256) void TimeAttention_38345468019460_kernel(
    const int*   __restrict__ concepts,   // [B*T]
    const int*   __restrict__ tts,        // [B*T]
    const int*   __restrict__ cts,        // [B*C]
    const int*   __restrict__ mask,       // [B*C]
    const float* __restrict__ emb,        // [VOCAB*W]
    float*       __restrict__ out)        // [B*T*C]
{
    const int wid  = threadIdx.x >> 6;          // wave in block (0..3)
    const int lane = threadIdx.x & 63;
    // wave-uniform row -> SGPR: concept/tts/emb-end loads scalarize
    const int row  = __builtin_amdgcn_readfirstlane((blockIdx.x << 2) + wid);
    const int b    = row >> 9;                  // T = 512
    const int tadj    = tts[row] - HALF;        // d = delta + HALF
    const float* erow = emb + (long)concepts[row] * WW;   // uniform base

    // Window ends: ~98% of the 512 deltas clip to d=0 or d=100.
    // Uniform loads + shared exp: the common path needs NO gather and NO exp.
    const float pe0   = __expf(erow[0]);
    const float pe100 = __expf(erow[WW - 1]);

    // Each lane owns 8 contiguous context slots.
    const int cbase = b * CC + lane * 8;
    int4 ct0 = *(const int4*)(cts  + cbase);
    int4 ct1 = *(const int4*)(cts  + cbase + 4);
    int4 mk0 = *(const int4*)(mask + cbase);
    int4 mk1 = *(const int4*)(mask + cbase + 4);
    int cc[8] = {ct0.x, ct0.y, ct0.z, ct0.w, ct1.x, ct1.y, ct1.z, ct1.w};
    int mm[8] = {mk0.x, mk0.y, mk0.z, mk0.w, mk1.x, mk1.y, mk1.z, mk1.w};

    // No-max softmax (validated R3: absmax 2.4e-4): masked -> exactly 0.
    float p[8];
    float s = 0.0f;
    #pragma unroll
    for (int j = 0; j < 8; ++j) {
        const int d = cc[j] - tadj;             // unclipped window index
        float v = (d <= 0) ? pe0 : pe100;       // both clipped ends, pre-exp'd
        if (d > 0 && d < WW - 1) {              // rare interior (~2% of lanes)
            v = __expf(erow[d]);                // exec-masked gather, 1-2 lines/wave
        }
        p[j] = mm[j] ? 0.0f : v;
        s += p[j];
    }

    // Wave-wide sum (64 lanes)
    #pragma unroll
    for (int off = 32; off; off >>= 1) s += __shfl_xor(s, off);

    const float inv = __builtin_amdgcn_rcpf(s);
    vfloat4 o0 = {p[0] * inv, p[1] * inv, p[2] * inv, p[3] * inv};
    vfloat4 o1 = {p[4] * inv, p[5] * inv, p[6] * inv, p[7] * inv};

    const long obase = (long)row * CC + lane * 8;
    __builtin_nontemporal_store(o0, (vfloat4*)(out + obase));   // streamed output
    __builtin_nontemporal_store(o1, (vfloat4*)(out + obase + 4));
}

extern "C" void kernel_launch(void* const* d_in, const int* in_sizes, int n_in,
                              void* d_out, int out_size, void* d_ws, size_t ws_size,
                              hipStream_t stream) {
    const int*   concepts = (const int*)d_in[0];
    const int*   tts      = (const int*)d_in[1];
    const int*   cts      = (const int*)d_in[2];
    const int*   mask     = (const int*)d_in[3];
    const float* emb      = (const float*)d_in[4];
    float*       out      = (float*)d_out;

    const int blocks = ROWS / 4;   // 8192 blocks, 4 waves (rows) each — R3 config
    TimeAttention_38345468019460_kernel<<<blocks, 256, 0, stream>>>(
        concepts, tts, cts, mask, emb, out);
}

// Round 8
// 20.934 us; speedup vs baseline: 1.8773x; 1.0806x over previous
//
#include <hip/hip_runtime.h>
#include <hip/hip_bf16.h>

// Problem constants (match reference)
#define VOCAB 50000
#define BB 64
#define TT 512
#define CC 512
#define HALF 50
#define WW 101            // window = 2*HALF+1
#define ROWS (BB * TT)    // 32768 rows, one wave each (R3 structure: best = 21.7us)

typedef float vfloat4 __attribute__((ext_vector_type(4)));

// Wave64 sum via DPP (rocPRIM pattern): row_shr 1,2,4,8 then row_bcast 15,31.
// 6 dependent VALU ops (~8cyc each) instead of 6 ds_permute round-trips (~35cyc each).
// DPP ctrl must be a literal constant -> template parameter.
template <int CTRL>
__device__ __forceinline__ float dpp_add_step(float x) {
    // old=0 & bound_ctrl=false: lanes with no valid source contribute 0.
    int t = __builtin_amdgcn_update_dpp(0, __float_as_int(x), CTRL, 0xf, 0xf, false);
    return x + __int_as_float(t);
}

__global__ __launch_bounds__(256) void TimeAttention_38345468019460_kernel(
    const int*   __restrict__ concepts,   // [B*T]
    const int*   __restrict__ tts,        // [B*T]
    const int*   __restrict__ cts,        // [B*C]
    const int*   __restrict__ mask,       // [B*C]
    const float* __restrict__ emb,        // [VOCAB*W]
    float*       __restrict__ out)        // [B*T*C]
{
    const int wid  = threadIdx.x >> 6;          // wave index within block (0..3)
    const int lane = threadIdx.x & 63;
    // row is wave-uniform: pin it to an SGPR so concept/timestamp loads scalarize
    const int row  = __builtin_amdgcn_readfirstlane((blockIdx.x << 2) + wid);
    const int b    = row >> 9;                  // T = 512
    const int tadj    = tts[row] - HALF;        // fold +HALF into the clamp
    const int concept = concepts[row];

    // Stage this row's 101-float embedding window into a WAVE-PRIVATE LDS slab.
    __shared__ float semb[4][104];
    const float* erow = emb + (long)concept * WW;
    semb[wid][lane] = erow[lane];                                // lanes 0..63
    if (lane < WW - 64) semb[wid][lane + 64] = erow[lane + 64];  // lanes 0..36
    __builtin_amdgcn_wave_barrier();  // wave-private region: no block barrier

    // Each lane handles 8 contiguous context slots.
    const int cbase = b * CC + lane * 8;
    int4 ct0 = *(const int4*)(cts  + cbase);
    int4 ct1 = *(const int4*)(cts  + cbase + 4);
    int4 mk0 = *(const int4*)(mask + cbase);
    int4 mk1 = *(const int4*)(mask + cbase + 4);

    int cc[8] = {ct0.x, ct0.y, ct0.z, ct0.w, ct1.x, ct1.y, ct1.z, ct1.w};
    int mm[8] = {mk0.x, mk0.y, mk0.z, mk0.w, mk1.x, mk1.y, mk1.z, mk1.w};

    // No-max softmax (validated: absmax 2.4e-4): masked -> exp(-1e9) = 0.
    float p[8];
    float s = 0.0f;
    #pragma unroll
    for (int j = 0; j < 8; ++j) {
        int d = cc[j] - tadj;
        d = min(max(d, 0), WW - 1);                    // v_sub + v_med3
        float v = semb[wid][d] + (float)mm[j] * (-1e9f);
        p[j] = __expf(v);
        s += p[j];
    }

    // Wave-wide sum: DPP chain, total lands in lane 63, broadcast via readlane.
    s = dpp_add_step<0x111>(s);   // row_shr:1
    s = dpp_add_step<0x112>(s);   // row_shr:2
    s = dpp_add_step<0x114>(s);   // row_shr:4
    s = dpp_add_step<0x118>(s);   // row_shr:8
    s = dpp_add_step<0x142>(s);   // row_bcast:15
    s = dpp_add_step<0x143>(s);   // row_bcast:31
    const float stot = __int_as_float(__builtin_amdgcn_readlane(__float_as_int(s), 63));

    const float inv = __builtin_amdgcn_rcpf(stot);
    vfloat4 o0 = {p[0] * inv, p[1] * inv, p[2] * inv, p[3] * inv};
    vfloat4 o1 = {p[4] * inv, p[5] * inv, p[6] * inv, p[7] * inv};

    const long obase = (long)row * CC + lane * 8;
    __builtin_nontemporal_store(o0, (vfloat4*)(out + obase));      // streamed output
    __builtin_nontemporal_store(o1, (vfloat4*)(out + obase + 4));
}

extern "C" void kernel_launch(void* const* d_in, const int* in_sizes, int n_in,
                              void* d_out, int out_size, void* d_ws, size_t ws_size,
                              hipStream_t stream) {
    const int*   concepts = (const int*)d_in[0];
    const int*   tts      = (const int*)d_in[1];
    const int*   cts      = (const int*)d_in[2];
    const int*   mask     = (const int*)d_in[3];
    const float* emb      = (const float*)d_in[4];
    float*       out      = (float*)d_out;

    const int blocks = ROWS / 4;   // 8192 blocks, 4 waves (rows) each
    TimeAttention_38345468019460_kernel<<<blocks, 256, 0, stream>>>(
        concepts, tts, cts, mask, emb, out);
}